// Round 1
// baseline (972.670 us; speedup 1.0000x reference)
//
#include <hip/hip_runtime.h>
#include <cstddef>

#define LSLOPE 0.2f
#define BN_EPS 1e-5f

__device__ __forceinline__ float lrelu(float x) { return x > 0.f ? x : LSLOPE * x; }

// ---------------- tiled fp32 GEMM: C[N,M] = A[N,K] @ B[K,M] (+bias) ----------------
template<int BN_, int TN_>
__global__ __launch_bounds__(256) void sgemm_k(const float* __restrict__ A, const float* __restrict__ B,
                                               float* __restrict__ C, int N, int K, int M,
                                               const float* __restrict__ bias) {
  constexpr int BM = 64;
  constexpr int BK = 32;
  constexpr int TM = 4;
  __shared__ float As[BK][BM + 4];
  __shared__ float Bs[BK][BN_ + 4];
  const int tid  = threadIdx.x;
  const int row0 = blockIdx.y * BM;
  const int col0 = blockIdx.x * BN_;
  const int rm   = (tid >> 4) * TM;
  const int cn   = (tid & 15) * TN_;
  float acc[TM][TN_];
#pragma unroll
  for (int i = 0; i < TM; ++i)
#pragma unroll
    for (int j = 0; j < TN_; ++j) acc[i][j] = 0.f;

  for (int kk = 0; kk < K; kk += BK) {
    for (int f = tid; f < BM * BK / 4; f += 256) {
      int ar = f / (BK / 4);
      int ac = (f % (BK / 4)) * 4;
      float4 v = make_float4(0.f, 0.f, 0.f, 0.f);
      int gr = row0 + ar;
      if (gr < N) v = *(const float4*)&A[(size_t)gr * K + kk + ac];
      As[ac + 0][ar] = v.x; As[ac + 1][ar] = v.y; As[ac + 2][ar] = v.z; As[ac + 3][ar] = v.w;
    }
    for (int f = tid; f < BK * BN_ / 4; f += 256) {
      int br = f / (BN_ / 4);
      int bc = (f % (BN_ / 4)) * 4;
      float4 v = *(const float4*)&B[(size_t)(kk + br) * M + col0 + bc];
      *(float4*)&Bs[br][bc] = v;
    }
    __syncthreads();
#pragma unroll
    for (int k = 0; k < BK; ++k) {
      float a[TM], b[TN_];
      float4 a0 = *(const float4*)&As[k][rm];
      a[0] = a0.x; a[1] = a0.y; a[2] = a0.z; a[3] = a0.w;
#pragma unroll
      for (int j0 = 0; j0 < TN_; j0 += 4) {
        float4 b0 = *(const float4*)&Bs[k][cn + j0];
        b[j0] = b0.x; b[j0 + 1] = b0.y; b[j0 + 2] = b0.z; b[j0 + 3] = b0.w;
      }
#pragma unroll
      for (int i = 0; i < TM; ++i)
#pragma unroll
        for (int j = 0; j < TN_; ++j) acc[i][j] = fmaf(a[i], b[j], acc[i][j]);
    }
    __syncthreads();
  }
#pragma unroll
  for (int i = 0; i < TM; ++i) {
    int gr = row0 + rm + i;
    if (gr >= N) continue;
#pragma unroll
    for (int j0 = 0; j0 < TN_; j0 += 4) {
      float4 v;
      v.x = acc[i][j0 + 0]; v.y = acc[i][j0 + 1]; v.z = acc[i][j0 + 2]; v.w = acc[i][j0 + 3];
      if (bias) {
        v.x += bias[col0 + cn + j0 + 0]; v.y += bias[col0 + cn + j0 + 1];
        v.z += bias[col0 + cn + j0 + 2]; v.w += bias[col0 + cn + j0 + 3];
      }
      *(float4*)&C[(size_t)gr * M + col0 + cn + j0] = v;
    }
  }
}

// ---------------- row-wise matvec: out[r] = A[r,:] . v (one wave per row) ----------------
__global__ __launch_bounds__(256) void matvec_k(const float* __restrict__ A, const float* __restrict__ v,
                                                float* __restrict__ out, int R, int K) {
  int w = (blockIdx.x * blockDim.x + threadIdx.x) >> 6;
  int lane = threadIdx.x & 63;
  if (w >= R) return;
  const float* row = A + (size_t)w * K;
  float s = 0.f;
  for (int k = lane; k < K; k += 64) s = fmaf(row[k], v[k], s);
#pragma unroll
  for (int off = 32; off; off >>= 1) s += __shfl_xor(s, off, 64);
  if (lane == 0) out[w] = s;
}

// ---------------- CSR build ----------------
__global__ void deg_count_k(const int* __restrict__ edst, int E, int N, int* __restrict__ deg) {
  int i = blockIdx.x * 256 + threadIdx.x;
  if (i >= E + N) return;
  int d = (i < E) ? edst[i] : (i - E);
  atomicAdd(&deg[d], 1);
}

__global__ __launch_bounds__(1024) void scan1_k(const int* __restrict__ deg, int n,
                                                int* __restrict__ ex, int* __restrict__ bsum) {
  __shared__ int sm[1024];
  int t = threadIdx.x;
  int idx = blockIdx.x * 1024 + t;
  int v = (idx < n) ? deg[idx] : 0;
  sm[t] = v;
  __syncthreads();
  for (int off = 1; off < 1024; off <<= 1) {
    int tv = (t >= off) ? sm[t - off] : 0;
    __syncthreads();
    sm[t] += tv;
    __syncthreads();
  }
  if (idx < n) ex[idx] = sm[t] - v;
  if (t == 1023) bsum[blockIdx.x] = sm[t];
}

__global__ void scan2_k(int* __restrict__ bsum, int nb) {
  if (threadIdx.x == 0 && blockIdx.x == 0) {
    int run = 0;
    for (int b = 0; b < nb; ++b) { int x = bsum[b]; bsum[b] = run; run += x; }
  }
}

__global__ void scan3_k(int* __restrict__ ex, const int* __restrict__ bsum, int n, int total,
                        int* __restrict__ cursor) {
  int idx = blockIdx.x * 256 + threadIdx.x;
  if (idx < n) {
    int v = ex[idx] + bsum[idx >> 10];
    ex[idx] = v;
    cursor[idx] = v;
  }
  if (idx == 0) ex[n] = total;
}

__global__ void scatter_k(const int* __restrict__ esrc, const int* __restrict__ edst, int E, int N,
                          int* __restrict__ cursor, int* __restrict__ csr_src) {
  int i = blockIdx.x * 256 + threadIdx.x;
  if (i >= E + N) return;
  int d, s;
  if (i < E) { d = edst[i]; s = esrc[i]; } else { d = i - E; s = d; }
  int pos = atomicAdd(&cursor[d], 1);
  csr_src[pos] = s;
}

// ---------------- GAT aggregation: one wave per dst node ----------------
__global__ __launch_bounds__(256) void gat_agg_k(const float* __restrict__ hsrc, const float* __restrict__ a_src,
                                                 const float* __restrict__ a_dst, const int* __restrict__ rowstart,
                                                 const int* __restrict__ csr_src, const float* __restrict__ bias,
                                                 float* __restrict__ outp, int N) {
  int w = (blockIdx.x * blockDim.x + threadIdx.x) >> 6;
  int lane = threadIdx.x & 63;
  if (w >= N) return;
  int s0 = rowstart[w];
  int s1 = rowstart[w + 1];
  int deg = s1 - s0;
  float ad = a_dst[w];

  // first (<=64) edges stay in registers
  int sA = 0;
  float eA = -3.0e38f;
  if (lane < deg) {
    sA = csr_src[s0 + lane];
    eA = lrelu(a_src[sA] + ad);
  }
  float m = eA;
  for (int j = s0 + 64 + lane; j < s1; j += 64) {
    int s = csr_src[j];
    m = fmaxf(m, lrelu(a_src[s] + ad));
  }
#pragma unroll
  for (int off = 32; off; off >>= 1) m = fmaxf(m, __shfl_xor(m, off, 64));

  float preg = (lane < deg) ? __expf(eA - m) : 0.f;
  float den = preg;
  for (int j = s0 + 64 + lane; j < s1; j += 64) {
    int s = csr_src[j];
    den += __expf(lrelu(a_src[s] + ad) - m);
  }
#pragma unroll
  for (int off = 32; off; off >>= 1) den += __shfl_xor(den, off, 64);
  float inv = 1.f / den;

  float accx = 0.f, accy = 0.f;
  int lim = deg < 64 ? deg : 64;
  for (int jj = 0; jj < lim; ++jj) {
    int s = __shfl(sA, jj, 64);
    float wgt = __shfl(preg, jj, 64) * inv;
    float2 hv = *(const float2*)&hsrc[(size_t)s * 128 + 2 * lane];
    accx = fmaf(wgt, hv.x, accx);
    accy = fmaf(wgt, hv.y, accy);
  }
  for (int j = s0 + 64; j < s1; ++j) {  // rare: deg > 64
    int s = csr_src[j];
    float wgt = __expf(lrelu(a_src[s] + ad) - m) * inv;
    float2 hv = *(const float2*)&hsrc[(size_t)s * 128 + 2 * lane];
    accx = fmaf(wgt, hv.x, accx);
    accy = fmaf(wgt, hv.y, accy);
  }
  float2 bv = *(const float2*)&bias[2 * lane];
  accx = fmaxf(accx + bv.x, 0.f);
  accy = fmaxf(accy + bv.y, 0.f);
  float2 o; o.x = accx; o.y = accy;
  *(float2*)&outp[(size_t)w * 128 + 2 * lane] = o;
}

// ---------------- BatchNorm stats / finalize ----------------
__global__ __launch_bounds__(256) void bn_stats_k(const float* __restrict__ z, int N,
                                                  float* __restrict__ sums, float* __restrict__ sumsq) {
  __shared__ float ls[256], lq[256];
  int col = threadIdx.x & 63;
  int rg = threadIdx.x >> 6;
  float s = 0.f, q = 0.f;
  for (int r = blockIdx.x * 4 + rg; r < N; r += gridDim.x * 4) {
    float v = z[(size_t)r * 64 + col];
    s += v;
    q = fmaf(v, v, q);
  }
  ls[threadIdx.x] = s;
  lq[threadIdx.x] = q;
  __syncthreads();
  if (threadIdx.x < 64) {
    s = ls[col] + ls[col + 64] + ls[col + 128] + ls[col + 192];
    q = lq[col] + lq[col + 64] + lq[col + 128] + lq[col + 192];
    atomicAdd(&sums[col], s);
    atomicAdd(&sumsq[col], q);
  }
}

__global__ void bn_finalize_k(const float* __restrict__ sums, const float* __restrict__ sumsq,
                              const float* __restrict__ gamma, const float* __restrict__ beta,
                              int N, float* __restrict__ scale, float* __restrict__ shift) {
  int c = threadIdx.x;
  if (c >= 64) return;
  float mean = sums[c] / (float)N;
  float var = sumsq[c] / (float)N - mean * mean;
  float rs = rsqrtf(var + BN_EPS);
  float sc = gamma[c] * rs;
  scale[c] = sc;
  shift[c] = beta[c] - mean * sc;
}

// ---------------- fused BN-apply + ReLU + FC2 + log_softmax (thread per node) ----------------
__global__ __launch_bounds__(256) void fc2_lsm_k(const float* __restrict__ z, const float* __restrict__ scale,
                                                 const float* __restrict__ shift, const float* __restrict__ w,
                                                 const float* __restrict__ b, float* __restrict__ out, int N) {
  int n = blockIdx.x * 256 + threadIdx.x;
  if (n >= N) return;
  float o[40];
#pragma unroll
  for (int c = 0; c < 40; ++c) o[c] = b[c];
  const float* zr = z + (size_t)n * 64;
  for (int k = 0; k < 64; ++k) {
    float v = fmaxf(fmaf(zr[k], scale[k], shift[k]), 0.f);
#pragma unroll
    for (int c = 0; c < 40; ++c) o[c] = fmaf(v, w[k * 40 + c], o[c]);
  }
  float mx = o[0];
#pragma unroll
  for (int c = 1; c < 40; ++c) mx = fmaxf(mx, o[c]);
  float s = 0.f;
#pragma unroll
  for (int c = 0; c < 40; ++c) s += __expf(o[c] - mx);
  float ls = __logf(s);
  float* orow = out + (size_t)n * 40;
#pragma unroll
  for (int c = 0; c < 40; ++c) orow[c] = o[c] - mx - ls;
}

// ---------------- launch ----------------
extern "C" void kernel_launch(void* const* d_in, const int* in_sizes, int n_in,
                              void* d_out, int out_size, void* d_ws, size_t ws_size,
                              hipStream_t stream) {
  const float* x     = (const float*)d_in[0];
  const int*   eidx  = (const int*)d_in[1];
  const float* W1s   = (const float*)d_in[2];
  const float* W1d   = (const float*)d_in[3];
  const float* att1s = (const float*)d_in[4];
  const float* att1d = (const float*)d_in[5];
  const float* b1    = (const float*)d_in[6];
  const float* W2s   = (const float*)d_in[7];
  const float* W2d   = (const float*)d_in[8];
  const float* att2s = (const float*)d_in[9];
  const float* att2d = (const float*)d_in[10];
  const float* b2    = (const float*)d_in[11];
  const float* fc1w  = (const float*)d_in[12];
  const float* fc1b  = (const float*)d_in[13];
  const float* gamma = (const float*)d_in[14];
  const float* beta  = (const float*)d_in[15];
  const float* fc2w  = (const float*)d_in[16];
  const float* fc2b  = (const float*)d_in[17];
  float* out = (float*)d_out;

  const int N  = in_sizes[0] / 256;
  const int E  = in_sizes[1] / 2;
  const int ET = E + N;
  const int DIN = 256, H1 = 128, H2 = 128, FCD = 64;

  // workspace layout (~112 MB)
  char* p = (char*)d_ws;
  const size_t NB = (size_t)N * 128 * sizeof(float);
  float* hA = (float*)p;       p += NB;
  float* hB = (float*)p;       p += NB;
  int* deg      = (int*)p;     p += (size_t)N * 4;
  int* rowstart = (int*)p;     p += (size_t)(N + 1) * 4;
  int* cursor   = (int*)p;     p += (size_t)N * 4;
  int* csr_src  = (int*)p;     p += (size_t)ET * 4;
  float* a_src  = (float*)p;   p += (size_t)N * 4;
  float* a_dst  = (float*)p;   p += (size_t)N * 4;
  float* wv     = (float*)p;   p += 256 * 4;
  float* sums   = (float*)p;   p += 64 * 4;
  float* sumsq  = (float*)p;   p += 64 * 4;
  float* scale  = (float*)p;   p += 64 * 4;
  float* shift  = (float*)p;   p += 64 * 4;
  int* bsum     = (int*)p;     p += 256 * 4;

  const int* esrc = eidx;
  const int* edst = eidx + E;

  // ---- CSR build (by dst, self-loops appended) ----
  hipMemsetAsync(deg, 0, (size_t)N * 4, stream);
  deg_count_k<<<(ET + 255) / 256, 256, 0, stream>>>(edst, E, N, deg);
  int nb = (N + 1023) / 1024;
  scan1_k<<<nb, 1024, 0, stream>>>(deg, N, rowstart, bsum);
  scan2_k<<<1, 64, 0, stream>>>(bsum, nb);
  scan3_k<<<(N + 255) / 256, 256, 0, stream>>>(rowstart, bsum, N, ET, cursor);
  scatter_k<<<(ET + 255) / 256, 256, 0, stream>>>(esrc, edst, E, N, cursor, csr_src);

  // ---- GAT layer 1 ----
  sgemm_k<128, 8><<<dim3(1, (N + 63) / 64), 256, 0, stream>>>(x, W1s, hA, N, DIN, H1, (const float*)nullptr);
  matvec_k<<<(DIN + 3) / 4, 256, 0, stream>>>(W1d, att1d, wv, DIN, H1);       // wv = W1_dst @ att1_dst
  matvec_k<<<(N + 3) / 4, 256, 0, stream>>>(x, wv, a_dst, N, DIN);            // a_dst = x @ wv
  matvec_k<<<(N + 3) / 4, 256, 0, stream>>>(hA, att1s, a_src, N, H1);         // a_src = h_src @ att1_src
  gat_agg_k<<<(N + 3) / 4, 256, 0, stream>>>(hA, a_src, a_dst, rowstart, csr_src, b1, hB, N);

  // ---- GAT layer 2 ----
  sgemm_k<128, 8><<<dim3(1, (N + 63) / 64), 256, 0, stream>>>(hB, W2s, hA, N, H1, H2, (const float*)nullptr);
  matvec_k<<<(H1 + 3) / 4, 256, 0, stream>>>(W2d, att2d, wv, H1, H2);
  matvec_k<<<(N + 3) / 4, 256, 0, stream>>>(hB, wv, a_dst, N, H1);
  matvec_k<<<(N + 3) / 4, 256, 0, stream>>>(hA, att2s, a_src, N, H2);
  gat_agg_k<<<(N + 3) / 4, 256, 0, stream>>>(hA, a_src, a_dst, rowstart, csr_src, b2, hB, N);

  // ---- FC1 (+bias) -> BN -> fused BN-apply+ReLU+FC2+log_softmax ----
  sgemm_k<64, 4><<<dim3(1, (N + 63) / 64), 256, 0, stream>>>(hB, fc1w, hA, N, H2, FCD, fc1b);
  hipMemsetAsync(sums, 0, 128 * sizeof(float), stream);
  bn_stats_k<<<512, 256, 0, stream>>>(hA, N, sums, sumsq);
  bn_finalize_k<<<1, 64, 0, stream>>>(sums, sumsq, gamma, beta, N, scale, shift);
  fc2_lsm_k<<<(N + 255) / 256, 256, 0, stream>>>(hA, scale, shift, fc2w, fc2b, out, N);
}